// Round 16
// baseline (227.943 us; speedup 1.0000x reference)
//
#include <hip/hip_runtime.h>
#include <hip/hip_bf16.h>

#define NN     500000
#define DIN    256
#define DATT   128
#define NG     4096
#define MT     16
#define NT16   31250      // NN / 16, exact (no partial tiles)
#define NBLOCKS 1024      // 4 per CU (16 waves/CU at <=128 VGPR)
#define TPB    31         // ceil(31250/1024); 1024*31 = 31744

typedef __attribute__((ext_vector_type(8))) short short8;
typedef __attribute__((ext_vector_type(4))) float f32x4;

// pack two f32 -> two bf16 (round-half-up)
__device__ __forceinline__ unsigned int pack2bf(float a, float b) {
    unsigned int ua = __float_as_uint(a) + 0x8000u;
    unsigned int ub = __float_as_uint(b) + 0x8000u;
    return __builtin_amdgcn_perm(ub, ua, 0x07060302);  // [ub.b3,ub.b2,ua.b3,ua.b2]
}

// tanh(x) = 1 - 2/(1+e^{2x})
__device__ __forceinline__ float tanh_fast(float v) {
    float e = __expf(2.f * v);
    return 1.f - 2.f * __builtin_amdgcn_rcpf(e + 1.f);
}

// LDS-only barrier: drains DS ops but leaves global loads in flight (T4).
__device__ __forceinline__ void lds_barrier() {
    asm volatile("s_waitcnt lgkmcnt(0)" ::: "memory");
    __builtin_amdgcn_s_barrier();
    asm volatile("" ::: "memory");
}

// one-time: W1 [256][128] fp32 -> W1t [128][256] bf16 (transposed) in d_ws
__global__ void prep_w1t(const float* __restrict__ W1, unsigned short* __restrict__ W1t) {
    int c = blockIdx.x;      // 0..127
    int k = threadIdx.x;     // 0..255
    unsigned int u = __float_as_uint(W1[k * DATT + c]) + 0x8000u;
    W1t[c * DIN + k] = (unsigned short)(u >> 16);
}

// 4-wave (256-thread) pipelined fused kernel, 4 blocks/CU -> 16 waves/CU.
// Each wave owns 32 h-cols (afr[16] = 64 VGPR) so only 4 waves sweep the
// x-tile's B-fragments (vs 8 in the prior 16-col config) -> GEMM LDS read
// traffic per node halves (it was the bound: ~3.1k cy/slot of ds_read_b128).
// MT=16 tile keeps pf[4]=16 VGPR so total ~123 < 128 cap. Double-buffered
// bf16 LDS; t+1 prefetch issued after barrier1, stays in flight across both
// lds_barriers (no vmcnt drain), consumed at next tile's pack2bf.
// Pooling: thread (q=tid&63 -> dims 4q..4q+3, wave w -> nodes 4w..4w+4)
// reads b64 quads from LDS, one acc4 carried across the block's contiguous
// sorted node range, atomic flush only at graph boundaries.
__global__ __launch_bounds__(256, 4)
void attnpool_kernel(const float* __restrict__ x,
                     const int* __restrict__ batch,
                     const unsigned short* __restrict__ W1t,
                     const float* __restrict__ b1,
                     const float* __restrict__ W2,
                     const float* __restrict__ b2,
                     float* __restrict__ out)
{
    __shared__ unsigned short xb[2][MT * DIN];   // 2 x 8 KB, XOR-swizzled
    __shared__ float part[4][MT];

    const int t0 = blockIdx.x * TPB;
    if (t0 >= NT16) return;
    const int tEnd = (t0 + TPB < NT16) ? t0 + TPB : NT16;

    const int tid = threadIdx.x;     // 0..255
    const int w   = tid >> 6;        // wave 0..3
    const int l   = tid & 63;
    const int lr  = l & 15;
    const int lg  = l >> 4;
    const int q   = tid & 63;        // pooled dim-quad (dims 4q..4q+3)

    // ---- per-block constants: A-frags (W1^T rows 32w..32w+31), biases
    short8 afr[16];
    {
        const unsigned short* A0 = W1t + (32 * w + lr) * DIN;
        #pragma unroll
        for (int kc = 0; kc < 8; ++kc) {
            afr[kc]     = *reinterpret_cast<const short8*>(A0 + 32 * kc + 8 * lg);
            afr[8 + kc] = *reinterpret_cast<const short8*>(A0 + 16 * DIN + 32 * kc + 8 * lg);
        }
    }
    float4 b1v[2], w2v[2];
    #pragma unroll
    for (int r2 = 0; r2 < 2; ++r2) {
        int c0 = 32 * w + 16 * r2 + 4 * lg;
        b1v[r2] = *reinterpret_cast<const float4*>(&b1[c0]);
        w2v[r2] = *reinterpret_cast<const float4*>(&W2[c0]);
    }
    const float b2s = b2[0];

    // ---- prologue: load tile t0 into pf (4 float4 = 16 VGPR)
    const float4* xg = (const float4*)x;
    float4 pf[4];
    {
        int base = t0 * (MT * 64);        // float4 index; max 32M < 2^31
        #pragma unroll
        for (int i = 0; i < 4; ++i) pf[i] = xg[base + tid + i * 256];
    }

    float4 acc4 = make_float4(0.f, 0.f, 0.f, 0.f);
    int gcur = -1;
    int cur = 0;

    for (int t = t0; t < tEnd; ++t) {
        // ---- stage tile t: pf -> xb[cur], bf16 swizzled
        unsigned short* X = xb[cur];
        #pragma unroll
        for (int i = 0; i < 4; ++i) {
            int j = tid + i * 256;        // float4-chunk id 0..1023
            int r = j >> 6, cc = j & 63;  // row 0..15
            int byte = r * 512 + ((cc * 8) ^ ((r & 7) << 4));
            *reinterpret_cast<uint2*>(reinterpret_cast<char*>(X) + byte) =
                make_uint2(pack2bf(pf[i].x, pf[i].y), pack2bf(pf[i].z, pf[i].w));
        }
        // per-wave batch ids for tile t (lanes 0..15 <-> nodes 0..15)
        int bvt = -1;
        if (l < 16) {
            int g = batch[t * MT + l];
            bvt = ((unsigned)g < NG) ? g : -1;
        }
        lds_barrier();                    // X ready; pf regs free; vmcnt NOT drained

        // ---- issue tile t+1 loads; land before next iteration's pack2bf
        if (t + 1 < tEnd) {
            int base = (t + 1) * (MT * 64);
            #pragma unroll
            for (int i = 0; i < 4; ++i) pf[i] = xg[base + tid + i * 256];
        }

        // ---- GEMM h^T: acc[r2] = h-cols [32w+16r2,+16) x nodes [0,16)
        f32x4 acc[2];
        acc[0] = (f32x4){0.f, 0.f, 0.f, 0.f};
        acc[1] = (f32x4){0.f, 0.f, 0.f, 0.f};

        #pragma unroll
        for (int kc = 0; kc < 8; ++kc) {
            int ko = 32 * kc + 8 * lg;
            int byte = lr * 512 + ((ko * 2) ^ ((lr & 7) << 4));
            short8 bfr = *reinterpret_cast<const short8*>(reinterpret_cast<const char*>(X) + byte);
            acc[0] = __builtin_amdgcn_mfma_f32_16x16x32_bf16(afr[kc],     bfr, acc[0], 0, 0, 0);
            acc[1] = __builtin_amdgcn_mfma_f32_16x16x32_bf16(afr[8 + kc], bfr, acc[1], 0, 0, 0);
        }

        // ---- attn partials: lane holds h[node=lr][col=32w+16r2+4lg+j]
        {
            float p = 0.f;
            #pragma unroll
            for (int r2 = 0; r2 < 2; ++r2) {
                p += tanh_fast(acc[r2][0] + b1v[r2].x) * w2v[r2].x;
                p += tanh_fast(acc[r2][1] + b1v[r2].y) * w2v[r2].y;
                p += tanh_fast(acc[r2][2] + b1v[r2].z) * w2v[r2].z;
                p += tanh_fast(acc[r2][3] + b1v[r2].w) * w2v[r2].w;
            }
            p += __shfl_xor(p, 16, 64);
            p += __shfl_xor(p, 32, 64);
            if (lg == 0) part[w][lr] = p;
        }
        lds_barrier();                    // part ready; vmcnt NOT drained

        // attn of node (l&15): sum 4 wave partials (broadcast LDS reads)
        const int nd = l & 15;
        float va = b2s + part[0][nd] + part[1][nd] + part[2][nd] + part[3][nd];

        // ---- pooling: wave w -> nodes [4w,4w+4), thread dims 4q..4q+3;
        // node ids strictly increase -> sorted; acc4 carried across tiles
        #pragma unroll
        for (int i = 0; i < 4; ++i) {
            int node = 4 * w + i;
            int   g = __builtin_amdgcn_readlane(bvt, node);
            float a = __int_as_float(__builtin_amdgcn_readlane(__float_as_int(va), node));
            if (g != gcur) {              // wave-uniform branch
                if (gcur >= 0) {
                    float* o = &out[gcur * DIN + 4 * q];
                    atomicAdd(o + 0, acc4.x); atomicAdd(o + 1, acc4.y);
                    atomicAdd(o + 2, acc4.z); atomicAdd(o + 3, acc4.w);
                }
                acc4 = make_float4(0.f, 0.f, 0.f, 0.f);
                gcur = g;
            }
            int byte = node * 512 + ((q * 8) ^ ((node & 7) << 4));
            uint2 xv = *reinterpret_cast<const uint2*>(reinterpret_cast<const char*>(X) + byte);
            acc4.x = fmaf(a, __uint_as_float(xv.x << 16),        acc4.x);
            acc4.y = fmaf(a, __uint_as_float(xv.x & 0xffff0000u), acc4.y);
            acc4.z = fmaf(a, __uint_as_float(xv.y << 16),        acc4.z);
            acc4.w = fmaf(a, __uint_as_float(xv.y & 0xffff0000u), acc4.w);
        }
        cur ^= 1;
    }
    if (gcur >= 0) {
        float* o = &out[gcur * DIN + 4 * q];
        atomicAdd(o + 0, acc4.x); atomicAdd(o + 1, acc4.y);
        atomicAdd(o + 2, acc4.z); atomicAdd(o + 3, acc4.w);
    }
}

extern "C" void kernel_launch(void* const* d_in, const int* in_sizes, int n_in,
                              void* d_out, int out_size, void* d_ws, size_t ws_size,
                              hipStream_t stream) {
    const float* x     = (const float*)d_in[0];
    const int*   batch = (const int*)d_in[1];     // int32 (JAX x64 disabled)
    const float* W1 = (const float*)d_in[3];
    const float* b1 = (const float*)d_in[4];
    const float* W2 = (const float*)d_in[5];
    const float* b2 = (const float*)d_in[6];
    float* out = (float*)d_out;
    unsigned short* W1t = (unsigned short*)d_ws;   // 64 KB

    hipMemsetAsync(out, 0, (size_t)NG * DIN * sizeof(float), stream);
    prep_w1t<<<DATT, DIN, 0, stream>>>(W1, W1t);
    attnpool_kernel<<<NBLOCKS, 256, 0, stream>>>(x, batch, W1t, b1, W2, b2, out);
}